// Round 8
// baseline (311.147 us; speedup 1.0000x reference)
//
#include <hip/hip_runtime.h>

typedef __attribute__((ext_vector_type(8))) short bf16x8;   // 8 bf16 (4 VGPRs)
typedef __attribute__((ext_vector_type(4))) float f32x4;    // MFMA accumulator

#define KSA 2    // split-K audio: 2 * 10 * 64 = 1280

// pack two f32 -> one dword of 2 bf16 (RNE), single HW instruction
__device__ __forceinline__ unsigned int pk2(float a, float b) {
    unsigned int r;
    asm("v_cvt_pk_bf16_f32 %0, %1, %2" : "=v"(r) : "v"(a), "v"(b));
    return r;
}

// global -> LDS direct copy, 16B per lane. LDS dest = wave-uniform base + lane*16.
__device__ __forceinline__ void gll16(void* lds, const void* g) {
    __builtin_amdgcn_global_load_lds(
        (__attribute__((address_space(1))) void*)(uintptr_t)g,
        (__attribute__((address_space(3))) void*)(uint32_t)(uintptr_t)lds,
        16, 0, 0);
}

// ---------------------------------------------------------------------------
// W transpose + f32->bf16:  W[K][512] -> Wt[512][K] bf16.
// Lane owns one output row n: reads W[k][n] (coalesced across lanes), packs,
// writes 32B contiguous per 16-k group. blocks: [0,1080) Wv, [1080,1100) Wa.
// ---------------------------------------------------------------------------
__global__ __launch_bounds__(256) void wtrans(
    const float* __restrict__ Wv, const float* __restrict__ Wa,
    unsigned short* __restrict__ Wt, unsigned short* __restrict__ Wat)
{
    const int b = blockIdx.x, tid = threadIdx.x;
    const float* src; unsigned short* dst; int K, kbase, n;
    if (b < 1080) { src = Wv; dst = Wt;  K = 69120; kbase = (b >> 1) * 128; n = (b & 1) * 256 + tid; }
    else { const int bb = b - 1080;
           src = Wa; dst = Wat; K = 1280;  kbase = (bb >> 1) * 128; n = (bb & 1) * 256 + tid; }

    const float* sp = src + n;
    unsigned short* dp = dst + (size_t)n * K + kbase;

    for (int kk = 0; kk < 128; kk += 16) {
        float v[16];
        #pragma unroll
        for (int i = 0; i < 16; ++i) v[i] = sp[(size_t)(kbase + kk + i) * 512];
        uint4 o0, o1;
        o0.x = pk2(v[0], v[1]);  o0.y = pk2(v[2], v[3]);
        o0.z = pk2(v[4], v[5]);  o0.w = pk2(v[6], v[7]);
        o1.x = pk2(v[8], v[9]);  o1.y = pk2(v[10], v[11]);
        o1.z = pk2(v[12], v[13]); o1.w = pk2(v[14], v[15]);
        *(uint4*)(dp + kk) = o0;
        *(uint4*)(dp + kk + 8) = o1;
    }
}

// ---------------------------------------------------------------------------
// GEMM: C[512,512] = A[512,K] * Bt^T, A = f32 rows (crop or plain), Bt = bf16
// [512][K]. Tile 128x128, BK=64, 256 thr = 4 waves (2x2 of 64x64). Split-K.
// B staged via global_load_lds (16B/lane) into [row][8 units] XOR row&7 layout
// (round-6 verified, 0 bank conflicts); A reg-staged f32->bf16, same layout.
// CROP=1: visual rows (stride 138240, center-crop); CROP=0: audio (1280).
// ---------------------------------------------------------------------------
template<int CROP>
__global__ __launch_bounds__(256, 3) void gemm_kernel(
    const float* __restrict__ s1, const float* __restrict__ s2,
    const unsigned short* __restrict__ Bt,
    float* __restrict__ part, int K, int ksteps)
{
    __shared__ uint4 As[1024];   // [128 rows][8 units of 8 bf16], unit ^= row&7
    __shared__ uint4 Bs[1024];

    const int tid = threadIdx.x;
    const int blk = blockIdx.x;
    const int cpx = gridDim.x >> 3;
    const int lin = (blk & 7) * cpx + (blk >> 3);   // XCD-chunked swizzle
    const int z  = lin >> 4;
    const int mn = lin & 15;
    const int m0 = (mn >> 2) * 128;
    const int n0 = (mn & 3) * 128;
    const int k0 = z * ksteps * 64;
    part += (size_t)z * 262144;

    const int wid = tid >> 6, lane = tid & 63;
    const int l15 = lane & 15, lk = lane >> 4;
    const int wm = (wid >> 1) * 64, wn = (wid & 1) * 64;

    // fragment LDS units (constant over K loop)
    int ua[2][4], ub[2][4];
    #pragma unroll
    for (int kh = 0; kh < 2; ++kh) {
        #pragma unroll
        for (int mi = 0; mi < 4; ++mi) {
            const int row = wm + mi * 16 + l15;
            ua[kh][mi] = row * 8 + ((kh * 4 + lk) ^ (row & 7));
        }
        #pragma unroll
        for (int ni = 0; ni < 4; ++ni) {
            const int nn = wn + ni * 16 + l15;
            ub[kh][ni] = nn * 8 + ((kh * 4 + lk) ^ (nn & 7));
        }
    }

    // B staging sources (advance 64 bf16 per step)
    const unsigned short* bsrc[4];
    #pragma unroll
    for (int i = 0; i < 4; ++i) {
        const int u = i * 256 + tid;
        const int rw = u >> 3, c = u & 7;
        bsrc[i] = Bt + (size_t)(n0 + rw) * K + k0 + ((c ^ (rw & 7)) * 8);
    }

    // A f32 staging: thread covers row = tid>>1, 4 of 8 k-chunks
    const int a_row = tid >> 1;
    const int grow = m0 + a_row;
    const int ROWSTR = CROP ? 138240 : 1280;
    const float* abase = (grow < 256) ? s1 + (size_t)grow * ROWSTR
                                      : s2 + (size_t)(grow - 256) * ROWSTR;

    f32x4 acc[4][4];
    #pragma unroll
    for (int mi = 0; mi < 4; ++mi)
        #pragma unroll
        for (int ni = 0; ni < 4; ++ni) acc[mi][ni] = f32x4{0.f, 0.f, 0.f, 0.f};

    int kc = k0;
    for (int ks = 0; ks < ksteps; ++ks) {
        // ---- stage B (async DMA) ----
        #pragma unroll
        for (int i = 0; i < 4; ++i)
            gll16(Bs + i * 256 + wid * 64, bsrc[i]);

        // ---- stage A (f32 -> bf16 pack); crop offset is block-uniform ----
        int aoffu;
        if (CROP) {
            // k-chunks of 4608 are contiguous at c*46080 + t*9216 + 4608 + j
            const int p = kc / 4608;
            const int j = kc - p * 4608;
            const int c3 = p % 3, t9 = p / 3;
            aoffu = c3 * 46080 + t9 * 9216 + 4608 + j;   // BK=64 never crosses
        } else {
            aoffu = kc;
        }
        #pragma unroll
        for (int x4 = 0; x4 < 4; ++x4) {
            const int x = (tid & 1) * 4 + x4;
            const float* ap = abase + aoffu + x * 8;
            const float4 f0 = *(const float4*)ap;
            const float4 f1 = *(const float4*)(ap + 4);
            uint4 pa;
            pa.x = pk2(f0.x, f0.y); pa.y = pk2(f0.z, f0.w);
            pa.z = pk2(f1.x, f1.y); pa.w = pk2(f1.z, f1.w);
            As[a_row * 8 + (x ^ (a_row & 7))] = pa;
        }
        __syncthreads();

        // ---- compute (2 k-halves x 16 MFMA) ----
        #pragma unroll
        for (int kh = 0; kh < 2; ++kh) {
            bf16x8 af[4], bfr[4];
            #pragma unroll
            for (int mi = 0; mi < 4; ++mi) af[mi] = __builtin_bit_cast(bf16x8, As[ua[kh][mi]]);
            #pragma unroll
            for (int ni = 0; ni < 4; ++ni) bfr[ni] = __builtin_bit_cast(bf16x8, Bs[ub[kh][ni]]);
            #pragma unroll
            for (int mi = 0; mi < 4; ++mi)
                #pragma unroll
                for (int ni = 0; ni < 4; ++ni)
                    acc[mi][ni] = __builtin_amdgcn_mfma_f32_16x16x32_bf16(af[mi], bfr[ni], acc[mi][ni], 0, 0, 0);
        }
        __syncthreads();

        kc += 64;
        #pragma unroll
        for (int i = 0; i < 4; ++i) bsrc[i] += 64;
    }

    // ---- epilogue: fp32 partials. C/D: col = lane&15, row = (lane>>4)*4+r
    #pragma unroll
    for (int mi = 0; mi < 4; ++mi)
        #pragma unroll
        for (int ni = 0; ni < 4; ++ni) {
            const int col = n0 + wn + ni * 16 + l15;
            #pragma unroll
            for (int r = 0; r < 4; ++r) {
                const int row = m0 + wm + mi * 16 + lk * 4 + r;
                part[(size_t)row * 512 + col] = acc[mi][ni][r];
            }
        }
}

// ---------- reduce split-K partials + row L2 normalization ----------
__global__ __launch_bounds__(256) void norm_kernel(
    const float* __restrict__ partA, const float* __restrict__ partV,
    float* __restrict__ Aout, float* __restrict__ Vout, int nzV)
{
    const int row = blockIdx.x;          // 0..1023
    const int tid = threadIdx.x;
    const bool isV = row >= 512;
    const int r = isV ? (row - 512) : row;
    const int c0 = tid, c1 = tid + 256;

    float v0 = 0.f, v1 = 0.f;
    if (isV) {
        for (int zz = 0; zz < nzV; ++zz) {
            const float* p = partV + (size_t)zz * 262144 + (size_t)r * 512;
            v0 += p[c0]; v1 += p[c1];
        }
    } else {
        #pragma unroll
        for (int zz = 0; zz < KSA; ++zz) {
            const float* p = partA + (size_t)zz * 262144 + (size_t)r * 512;
            v0 += p[c0]; v1 += p[c1];
        }
    }

    float ss = v0 * v0 + v1 * v1;
    #pragma unroll
    for (int off = 32; off > 0; off >>= 1) ss += __shfl_down(ss, off);
    __shared__ float sbuf[4];
    if ((tid & 63) == 0) sbuf[tid >> 6] = ss;
    __syncthreads();
    const float total = sbuf[0] + sbuf[1] + sbuf[2] + sbuf[3];
    const float inv = 1.f / fmaxf(sqrtf(total), 1e-12f);

    float* outp = (isV ? Vout : Aout) + (size_t)r * 512;
    outp[c0] = v0 * inv;
    outp[c1] = v1 * inv;
}

// ---------------------------------------------------------------------------
// similarity: S = Anorm . Vnorm^T (64x64 tiles, f32 in, bf16 MFMA),
// epilogue: den[row&255] += sum_col exp(S); diag-family exp -> num[row&255]
// ---------------------------------------------------------------------------
__global__ __launch_bounds__(256) void sim_kernel(
    const float* __restrict__ A, const float* __restrict__ V,
    float* __restrict__ den, float* __restrict__ num)
{
    __shared__ uint4 As[2][256];
    __shared__ uint4 Bs[2][256];

    const int tid = threadIdx.x;
    const int m0 = (blockIdx.x >> 3) * 64;
    const int n0 = (blockIdx.x & 7) * 64;
    const int nsteps = 16;               // K = 512

    const int a_row = tid >> 2, a_kb = tid & 3;
    const int b_col = tid & 63, b_kb = tid >> 6;
    const int a_u = (a_kb * 64 + a_row) ^ (a_kb << 1);
    const int b_u = (b_kb * 64 + b_col) ^ (b_kb << 1);

    const float* abase = A + (size_t)(m0 + a_row) * 512;
    const float* bptr  = V + (size_t)(n0 + b_col) * 512 + b_kb * 8;
    int aoff = a_kb * 8;

    const int lane = tid & 63, wid = tid >> 6;
    const int wrow = (wid >> 1) * 32, wcol = (wid & 1) * 32;
    const int l15 = lane & 15, lk = lane >> 4;

    int ra[2], rb[2];
    #pragma unroll
    for (int m = 0; m < 2; ++m) ra[m] = (lk * 64 + wrow + m * 16 + l15) ^ (lk << 1);
    #pragma unroll
    for (int n = 0; n < 2; ++n) rb[n] = (lk * 64 + wcol + n * 16 + l15) ^ (lk << 1);

    f32x4 acc[2][2];
    #pragma unroll
    for (int m = 0; m < 2; ++m)
        #pragma unroll
        for (int n = 0; n < 2; ++n) acc[m][n] = f32x4{0.f, 0.f, 0.f, 0.f};

    float4 A0 = *(const float4*)(abase + aoff);
    float4 A1 = *(const float4*)(abase + aoff + 4);
    float4 B0 = *(const float4*)bptr;
    float4 B1 = *(const float4*)(bptr + 4);

    for (int ks = 0; ks < nsteps; ++ks) {
        const int cur = ks & 1;
        const bool more = (ks + 1 < nsteps);
        float4 A0n, A1n, B0n, B1n;
        if (more) {
            aoff += 32; bptr += 32;
            A0n = *(const float4*)(abase + aoff);
            A1n = *(const float4*)(abase + aoff + 4);
            B0n = *(const float4*)bptr;
            B1n = *(const float4*)(bptr + 4);
        }
        uint4 pa;
        pa.x = pk2(A0.x, A0.y); pa.y = pk2(A0.z, A0.w);
        pa.z = pk2(A1.x, A1.y); pa.w = pk2(A1.z, A1.w);
        As[cur][a_u] = pa;
        uint4 pb;
        pb.x = pk2(B0.x, B0.y); pb.y = pk2(B0.z, B0.w);
        pb.z = pk2(B1.x, B1.y); pb.w = pk2(B1.z, B1.w);
        Bs[cur][b_u] = pb;
        __syncthreads();

        bf16x8 af[2], bfr[2];
        #pragma unroll
        for (int m = 0; m < 2; ++m) af[m] = __builtin_bit_cast(bf16x8, As[cur][ra[m]]);
        #pragma unroll
        for (int n = 0; n < 2; ++n) bfr[n] = __builtin_bit_cast(bf16x8, Bs[cur][rb[n]]);
        #pragma unroll
        for (int m = 0; m < 2; ++m)
            #pragma unroll
            for (int n = 0; n < 2; ++n)
                acc[m][n] = __builtin_amdgcn_mfma_f32_16x16x32_bf16(af[m], bfr[n], acc[m][n], 0, 0, 0);

        if (more) { A0 = A0n; A1 = A1n; B0 = B0n; B1 = B1n; }
    }

    #pragma unroll
    for (int m = 0; m < 2; ++m) {
        float rs[4] = {0.f, 0.f, 0.f, 0.f};
        #pragma unroll
        for (int n = 0; n < 2; ++n) {
            const int col = n0 + wcol + n * 16 + l15;
            #pragma unroll
            for (int r = 0; r < 4; ++r) {
                const int row = m0 + wrow + m * 16 + lk * 4 + r;
                const float e = __expf(acc[m][n][r]);
                rs[r] += e;
                if (((row - col) & 255) == 0) atomicAdd(num + (row & 255), e);
            }
        }
        #pragma unroll
        for (int r = 0; r < 4; ++r) {
            float v = rs[r];
            v += __shfl_xor(v, 1);
            v += __shfl_xor(v, 2);
            v += __shfl_xor(v, 4);
            v += __shfl_xor(v, 8);
            if (l15 == 0) {
                const int row = m0 + wrow + m * 16 + lk * 4 + r;
                atomicAdd(den + (row & 255), v);
            }
        }
    }
}

// ---------- zero den/num accumulators ----------
__global__ __launch_bounds__(512) void zero_kernel(float* __restrict__ p) {
    p[threadIdx.x] = 0.f;
}

// ---------- a1.a2 and v1.v2 dots -> num += exp(dot) ----------
__global__ __launch_bounds__(256) void dots_kernel(
    const float* __restrict__ A, const float* __restrict__ V,
    float* __restrict__ num)
{
    const int b = blockIdx.x;            // 0..511
    const int i = b & 255;
    const float* X = (b < 256) ? A : V;
    const float* x = X + (size_t)i * 512;
    const float* y = X + (size_t)(i + 256) * 512;
    const int tid = threadIdx.x;
    float d = x[tid] * y[tid] + x[tid + 256] * y[tid + 256];
    #pragma unroll
    for (int off = 32; off > 0; off >>= 1) d += __shfl_down(d, off);
    __shared__ float sbuf[4];
    if ((tid & 63) == 0) sbuf[tid >> 6] = d;
    __syncthreads();
    if (tid == 0) atomicAdd(num + i, __expf(sbuf[0] + sbuf[1] + sbuf[2] + sbuf[3]));
}

// ---------- final: loss = mean(log den - log num) ----------
__global__ __launch_bounds__(256) void final_kernel(
    const float* __restrict__ den, const float* __restrict__ num,
    float* __restrict__ out)
{
    const int tid = threadIdx.x;
    float v = logf(den[tid]) - logf(num[tid]);
    #pragma unroll
    for (int off = 32; off > 0; off >>= 1) v += __shfl_down(v, off);
    __shared__ float sbuf[4];
    if ((tid & 63) == 0) sbuf[tid >> 6] = v;
    __syncthreads();
    if (tid == 0) out[0] = (sbuf[0] + sbuf[1] + sbuf[2] + sbuf[3]) * (1.f / 256.f);
}

// ---------- launch ----------
extern "C" void kernel_launch(void* const* d_in, const int* in_sizes, int n_in,
                              void* d_out, int out_size, void* d_ws, size_t ws_size,
                              hipStream_t stream)
{
    (void)in_sizes; (void)n_in; (void)out_size;
    const float* a_1 = (const float*)d_in[0];
    const float* v_1 = (const float*)d_in[1];
    const float* a_2 = (const float*)d_in[2];
    const float* v_2 = (const float*)d_in[3];
    const float* W_a = (const float*)d_in[4];
    const float* W_v = (const float*)d_in[5];
    float* out = (float*)d_out;

    // ---- split-K tier by workspace (f32 part + bf16 Wt/Wat) ----
    auto need = [](int ksv) -> size_t {
        return (size_t)4 * (512 + 262144u * (4 + ksv))       // den/num/norms/partA/partV
             + (size_t)2 * (35389440u + 655360u);            // Wt + Wat bf16
    };
    int KSV;
    if      (ws_size >= need(45)) KSV = 45;
    else if (ws_size >= need(27)) KSV = 27;
    else                          KSV = 9;
    const int kstepsV = 1080 / KSV;   // 24 / 40 / 120

    float* cur   = (float*)d_ws;
    float* den   = cur; cur += 256;
    float* num   = cur; cur += 256;
    float* Anorm = cur; cur += 262144;
    float* Vnorm = cur; cur += 262144;
    float* partA = cur; cur += (size_t)KSA * 262144;
    float* partV = cur; cur += (size_t)KSV * 262144;
    unsigned short* Wt  = (unsigned short*)cur;
    unsigned short* Wat = Wt + 35389440u;

    zero_kernel<<<1, 512, 0, stream>>>(den);   // zeros den[256]+num[256]

    wtrans<<<1100, 256, 0, stream>>>(W_v, W_a, Wt, Wat);

    gemm_kernel<1><<<16 * KSV, 256, 0, stream>>>(v_1, v_2, Wt, partV, 69120, kstepsV);
    gemm_kernel<0><<<16 * KSA, 256, 0, stream>>>(a_1, a_2, Wat, partA, 1280, 10);

    norm_kernel<<<1024, 256, 0, stream>>>(partA, partV, Anorm, Vnorm, KSV);
    sim_kernel<<<64, 256, 0, stream>>>(Anorm, Vnorm, den, num);
    dots_kernel<<<512, 256, 0, stream>>>(Anorm, Vnorm, num);
    final_kernel<<<1, 256, 0, stream>>>(den, num, out);
}

// Round 9
// 248.986 us; speedup vs baseline: 1.2497x; 1.2497x over previous
//
#include <hip/hip_runtime.h>

typedef __attribute__((ext_vector_type(8))) short bf16x8;   // 8 bf16 (4 VGPRs)
typedef __attribute__((ext_vector_type(4))) float f32x4;
typedef __attribute__((ext_vector_type(2))) float f32x2;

#define ZV 72    // visual split-K: 72 * 30 * 32 = 69120
#define ZA 2     // audio  split-K:  2 * 20 * 32 = 1280

// pack two f32 -> one dword of 2 bf16 (RNE)
__device__ __forceinline__ unsigned int pk2(float a, float b) {
    unsigned int r;
    asm("v_cvt_pk_bf16_f32 %0, %1, %2" : "=v"(r) : "v"(a), "v"(b));
    return r;
}
// pinned global loads (issue point fixed, dest regs forced live)
__device__ __forceinline__ void gl4_0 (f32x4& d, const float* p) { asm volatile("global_load_dwordx4 %0, %1, off"            : "=&v"(d) : "v"(p)); }
__device__ __forceinline__ void gl4_16(f32x4& d, const float* p) { asm volatile("global_load_dwordx4 %0, %1, off offset:16"  : "=&v"(d) : "v"(p)); }
__device__ __forceinline__ void gl4_32(f32x4& d, const float* p) { asm volatile("global_load_dwordx4 %0, %1, off offset:32"  : "=&v"(d) : "v"(p)); }
__device__ __forceinline__ void gl4_48(f32x4& d, const float* p) { asm volatile("global_load_dwordx4 %0, %1, off offset:48"  : "=&v"(d) : "v"(p)); }
__device__ __forceinline__ void gl2_0 (f32x2& d, const float* p) { asm volatile("global_load_dwordx2 %0, %1, off"            : "=&v"(d) : "v"(p)); }
__device__ __forceinline__ void gl2_2k(f32x2& d, const float* p) { asm volatile("global_load_dwordx2 %0, %1, off offset:2048": "=&v"(d) : "v"(p)); }

__device__ __forceinline__ void waitv0() {
    asm volatile("s_waitcnt vmcnt(0)" ::: "memory");
    __builtin_amdgcn_sched_barrier(0);
}
__device__ __forceinline__ void barrier_lgkm() {
    asm volatile("s_waitcnt lgkmcnt(0)" ::: "memory");
    __builtin_amdgcn_sched_barrier(0);
    __builtin_amdgcn_s_barrier();
    __builtin_amdgcn_sched_barrier(0);
}
__device__ __forceinline__ void barrier_only() {
    __builtin_amdgcn_sched_barrier(0);
    __builtin_amdgcn_s_barrier();
    __builtin_amdgcn_sched_barrier(0);
}

// ---------------------------------------------------------------------------
// Fused GEMM: C[512,512] = A[512,K] * W[K,512], BOTH f32 straight from HBM.
// Tile 256x256, BK=32, 512 thr = 8 waves (2m x 4n; wave 128x64, acc 128 f32).
// LDS rows stride 80B (64B data + 16B pad): <=2-way banks, 16B aligned.
// A: reg-staged f32->bf16 (crop math uniform per step).
// B: per-thread gather of 8 float2 (2 n-cols x 8 k) from W's k-major rows.
// Pipeline: issue t+1 loads right after PACK t; raw s_barrier (no vmcnt drain).
// CROP=1: visual (row stride 138240, center crop); CROP=0: audio (1280).
// ---------------------------------------------------------------------------
template<int CROP>
__global__ __launch_bounds__(512, 2) void fgemm(
    const float* __restrict__ s1, const float* __restrict__ s2,
    const float* __restrict__ W, float* __restrict__ part, int nsteps)
{
    __shared__ unsigned char lds[40960];      // As [256 rows][80B] | Bs same
    unsigned char* Asb = lds;
    unsigned char* Bsb = lds + 20480;

    const int tid = threadIdx.x;
    const int blk = blockIdx.x;
    const int cpx = gridDim.x >> 3;
    const int lin = (blk & 7) * cpx + (blk >> 3);   // same-z tiles -> same XCD
    const int z    = lin >> 2;
    const int tile = lin & 3;
    const int m0 = (tile >> 1) * 256;
    const int n0 = (tile & 1) * 256;
    const int k0 = z * nsteps * 32;
    part += (size_t)z * 262144;

    // ---- A staging map: thread -> (row 0..255, k-half 0/1)
    const int a_row  = tid >> 1;
    const int a_half = tid & 1;
    const int grow = m0 + a_row;
    const int ROWSTR = CROP ? 138240 : 1280;
    const float* abase0 = (grow < 256) ? s1 + (size_t)grow * ROWSTR
                                       : s2 + (size_t)(grow - 256) * ROWSTR;
    const float* abase = abase0 + a_half * 16;

    // ---- B staging map: thread -> (n-pair 0..127, k-oct 0..3)
    const int b_np  = tid >> 2;        // n = 2*b_np, 2*b_np+1
    const int b_oct = tid & 3;         // k = oct*8 .. +7
    const float* bb0 = W + (size_t)(k0 + b_oct * 8) * 512 + n0 + 2 * b_np;
    const float* bb1 = bb0 + 1024;     // +2 k-rows
    const float* bb2 = bb0 + 2048;
    const float* bb3 = bb0 + 3072;

    // ---- wave / fragment map
    const int lane = tid & 63, wid = tid >> 6;
    const int l15 = lane & 15, lk = lane >> 4;
    const int wm = (wid >> 2) * 128;   // 2 m-groups
    const int wn = (wid & 3) * 64;     // 4 n-groups

    const unsigned char* arp[8];
    #pragma unroll
    for (int mi = 0; mi < 8; ++mi)
        arp[mi] = Asb + (wm + mi * 16 + l15) * 80 + lk * 16;
    const unsigned char* brp[4];
    #pragma unroll
    for (int ni = 0; ni < 4; ++ni)
        brp[ni] = Bsb + (wn + ni * 16 + l15) * 80 + lk * 16;

    f32x4 acc[8][4];
    #pragma unroll
    for (int mi = 0; mi < 8; ++mi)
        #pragma unroll
        for (int ni = 0; ni < 4; ++ni) acc[mi][ni] = f32x4{0.f, 0.f, 0.f, 0.f};

    f32x4 av[4];
    f32x2 bv[8];
    int kgs = k0;

    auto ISSUE = [&]() {
        const float* ap;
        if (CROP) {
            const int p = kgs / 4608;            // uniform; BK never straddles
            const int j = kgs - p * 4608;
            const int c3 = p % 3, t9 = p / 3;
            ap = abase + c3 * 46080 + t9 * 9216 + 4608 + j;
        } else {
            ap = abase + kgs;
        }
        gl4_0(av[0], ap); gl4_16(av[1], ap); gl4_32(av[2], ap); gl4_48(av[3], ap);
        gl2_0(bv[0], bb0); gl2_2k(bv[1], bb0);
        gl2_0(bv[2], bb1); gl2_2k(bv[3], bb1);
        gl2_0(bv[4], bb2); gl2_2k(bv[5], bb2);
        gl2_0(bv[6], bb3); gl2_2k(bv[7], bb3);
    };
    auto ADV = [&]() {
        kgs += 32;
        bb0 += 16384; bb1 += 16384; bb2 += 16384; bb3 += 16384;
    };
    auto PACK = [&]() {
        uint4 w0, w1;
        w0.x = pk2(av[0].x, av[0].y); w0.y = pk2(av[0].z, av[0].w);
        w0.z = pk2(av[1].x, av[1].y); w0.w = pk2(av[1].z, av[1].w);
        w1.x = pk2(av[2].x, av[2].y); w1.y = pk2(av[2].z, av[2].w);
        w1.z = pk2(av[3].x, av[3].y); w1.w = pk2(av[3].z, av[3].w);
        *(uint4*)(Asb + a_row * 80 + a_half * 32)      = w0;
        *(uint4*)(Asb + a_row * 80 + a_half * 32 + 16) = w1;
        uint4 bx, by;
        bx.x = pk2(bv[0].x, bv[1].x); bx.y = pk2(bv[2].x, bv[3].x);
        bx.z = pk2(bv[4].x, bv[5].x); bx.w = pk2(bv[6].x, bv[7].x);
        by.x = pk2(bv[0].y, bv[1].y); by.y = pk2(bv[2].y, bv[3].y);
        by.z = pk2(bv[4].y, bv[5].y); by.w = pk2(bv[6].y, bv[7].y);
        *(uint4*)(Bsb + (2 * b_np) * 80 + b_oct * 16)     = bx;
        *(uint4*)(Bsb + (2 * b_np + 1) * 80 + b_oct * 16) = by;
    };

    ISSUE();                                   // prologue: step 0
    for (int ks = 0; ks < nsteps; ++ks) {
        waitv0();                              // step-ks regs ready
        PACK();
        if (ks + 1 < nsteps) { ADV(); ISSUE(); }   // t+1 in flight across MFMA
        barrier_lgkm();                        // LDS writes visible (no vm drain)

        bf16x8 af[8], bf[4];
        #pragma unroll
        for (int mi = 0; mi < 8; ++mi) af[mi] = __builtin_bit_cast(bf16x8, *(const uint4*)arp[mi]);
        #pragma unroll
        for (int ni = 0; ni < 4; ++ni) bf[ni] = __builtin_bit_cast(bf16x8, *(const uint4*)brp[ni]);
        #pragma unroll
        for (int mi = 0; mi < 8; ++mi)
            #pragma unroll
            for (int ni = 0; ni < 4; ++ni)
                acc[mi][ni] = __builtin_amdgcn_mfma_f32_16x16x32_bf16(af[mi], bf[ni], acc[mi][ni], 0, 0, 0);

        barrier_only();                        // reads done before next PACK
    }

    // ---- epilogue: fp32 partials. C/D: col = lane&15, row = (lane>>4)*4+r
    #pragma unroll
    for (int mi = 0; mi < 8; ++mi)
        #pragma unroll
        for (int ni = 0; ni < 4; ++ni) {
            const int col = n0 + wn + ni * 16 + l15;
            #pragma unroll
            for (int r = 0; r < 4; ++r) {
                const int row = m0 + wm + mi * 16 + lk * 4 + r;
                part[(size_t)row * 512 + col] = acc[mi][ni][r];
            }
        }
}

// ---------- reduce split-K partials + row L2 normalization ----------
__global__ __launch_bounds__(256) void norm_kernel(
    const float* __restrict__ partA, const float* __restrict__ partV,
    float* __restrict__ Aout, float* __restrict__ Vout, int nzV)
{
    const int row = blockIdx.x;          // 0..1023
    const int tid = threadIdx.x;
    const bool isV = row >= 512;
    const int r = isV ? (row - 512) : row;
    const int c0 = tid, c1 = tid + 256;

    float v0 = 0.f, v1 = 0.f;
    if (isV) {
        for (int zz = 0; zz < nzV; ++zz) {
            const float* p = partV + (size_t)zz * 262144 + (size_t)r * 512;
            v0 += p[c0]; v1 += p[c1];
        }
    } else {
        #pragma unroll
        for (int zz = 0; zz < ZA; ++zz) {
            const float* p = partA + (size_t)zz * 262144 + (size_t)r * 512;
            v0 += p[c0]; v1 += p[c1];
        }
    }

    float ss = v0 * v0 + v1 * v1;
    #pragma unroll
    for (int off = 32; off > 0; off >>= 1) ss += __shfl_down(ss, off);
    __shared__ float sbuf[4];
    if ((tid & 63) == 0) sbuf[tid >> 6] = ss;
    __syncthreads();
    const float total = sbuf[0] + sbuf[1] + sbuf[2] + sbuf[3];
    const float inv = 1.f / fmaxf(sqrtf(total), 1e-12f);

    float* outp = (isV ? Vout : Aout) + (size_t)r * 512;
    outp[c0] = v0 * inv;
    outp[c1] = v1 * inv;
}

// ---------------------------------------------------------------------------
// similarity: S = Anorm . Vnorm^T (64x64 tiles, f32 in, bf16 MFMA),
// epilogue: den[row&255] += sum_col exp(S); diag-family exp -> num[row&255]
// ---------------------------------------------------------------------------
__global__ __launch_bounds__(256) void sim_kernel(
    const float* __restrict__ A, const float* __restrict__ V,
    float* __restrict__ den, float* __restrict__ num)
{
    __shared__ uint4 As[2][256];
    __shared__ uint4 Bs[2][256];

    const int tid = threadIdx.x;
    const int m0 = (blockIdx.x >> 3) * 64;
    const int n0 = (blockIdx.x & 7) * 64;
    const int nsteps = 16;               // K = 512

    const int a_row = tid >> 2, a_kb = tid & 3;
    const int b_col = tid & 63, b_kb = tid >> 6;
    const int a_u = (a_kb * 64 + a_row) ^ (a_kb << 1);
    const int b_u = (b_kb * 64 + b_col) ^ (b_kb << 1);

    const float* abase = A + (size_t)(m0 + a_row) * 512;
    const float* bptr  = V + (size_t)(n0 + b_col) * 512 + b_kb * 8;
    int aoff = a_kb * 8;

    const int lane = tid & 63, wid = tid >> 6;
    const int wrow = (wid >> 1) * 32, wcol = (wid & 1) * 32;
    const int l15 = lane & 15, lk = lane >> 4;

    int ra[2], rb[2];
    #pragma unroll
    for (int m = 0; m < 2; ++m) ra[m] = (lk * 64 + wrow + m * 16 + l15) ^ (lk << 1);
    #pragma unroll
    for (int n = 0; n < 2; ++n) rb[n] = (lk * 64 + wcol + n * 16 + l15) ^ (lk << 1);

    f32x4 acc[2][2];
    #pragma unroll
    for (int m = 0; m < 2; ++m)
        #pragma unroll
        for (int n = 0; n < 2; ++n) acc[m][n] = f32x4{0.f, 0.f, 0.f, 0.f};

    float4 A0 = *(const float4*)(abase + aoff);
    float4 A1 = *(const float4*)(abase + aoff + 4);
    float4 B0 = *(const float4*)bptr;
    float4 B1 = *(const float4*)(bptr + 4);

    for (int ks = 0; ks < nsteps; ++ks) {
        const int cur = ks & 1;
        const bool more = (ks + 1 < nsteps);
        float4 A0n, A1n, B0n, B1n;
        if (more) {
            aoff += 32; bptr += 32;
            A0n = *(const float4*)(abase + aoff);
            A1n = *(const float4*)(abase + aoff + 4);
            B0n = *(const float4*)bptr;
            B1n = *(const float4*)(bptr + 4);
        }
        uint4 pa;
        pa.x = pk2(A0.x, A0.y); pa.y = pk2(A0.z, A0.w);
        pa.z = pk2(A1.x, A1.y); pa.w = pk2(A1.z, A1.w);
        As[cur][a_u] = pa;
        uint4 pb;
        pb.x = pk2(B0.x, B0.y); pb.y = pk2(B0.z, B0.w);
        pb.z = pk2(B1.x, B1.y); pb.w = pk2(B1.z, B1.w);
        Bs[cur][b_u] = pb;
        __syncthreads();

        bf16x8 af[2], bfr[2];
        #pragma unroll
        for (int m = 0; m < 2; ++m) af[m] = __builtin_bit_cast(bf16x8, As[cur][ra[m]]);
        #pragma unroll
        for (int n = 0; n < 2; ++n) bfr[n] = __builtin_bit_cast(bf16x8, Bs[cur][rb[n]]);
        #pragma unroll
        for (int m = 0; m < 2; ++m)
            #pragma unroll
            for (int n = 0; n < 2; ++n)
                acc[m][n] = __builtin_amdgcn_mfma_f32_16x16x32_bf16(af[m], bfr[n], acc[m][n], 0, 0, 0);

        if (more) { A0 = A0n; A1 = A1n; B0 = B0n; B1 = B1n; }
    }

    #pragma unroll
    for (int m = 0; m < 2; ++m) {
        float rs[4] = {0.f, 0.f, 0.f, 0.f};
        #pragma unroll
        for (int n = 0; n < 2; ++n) {
            const int col = n0 + wcol + n * 16 + l15;
            #pragma unroll
            for (int r = 0; r < 4; ++r) {
                const int row = m0 + wrow + m * 16 + lk * 4 + r;
                const float e = __expf(acc[m][n][r]);
                rs[r] += e;
                if (((row - col) & 255) == 0) atomicAdd(num + (row & 255), e);
            }
        }
        #pragma unroll
        for (int r = 0; r < 4; ++r) {
            float v = rs[r];
            v += __shfl_xor(v, 1);
            v += __shfl_xor(v, 2);
            v += __shfl_xor(v, 4);
            v += __shfl_xor(v, 8);
            if (l15 == 0) {
                const int row = m0 + wrow + m * 16 + lk * 4 + r;
                atomicAdd(den + (row & 255), v);
            }
        }
    }
}

// ---------- zero den/num accumulators ----------
__global__ __launch_bounds__(512) void zero_kernel(float* __restrict__ p) {
    p[threadIdx.x] = 0.f;
}

// ---------- a1.a2 and v1.v2 dots -> num += exp(dot) ----------
__global__ __launch_bounds__(256) void dots_kernel(
    const float* __restrict__ A, const float* __restrict__ V,
    float* __restrict__ num)
{
    const int b = blockIdx.x;            // 0..511
    const int i = b & 255;
    const float* X = (b < 256) ? A : V;
    const float* x = X + (size_t)i * 512;
    const float* y = X + (size_t)(i + 256) * 512;
    const int tid = threadIdx.x;
    float d = x[tid] * y[tid] + x[tid + 256] * y[tid + 256];
    #pragma unroll
    for (int off = 32; off > 0; off >>= 1) d += __shfl_down(d, off);
    __shared__ float sbuf[4];
    if ((tid & 63) == 0) sbuf[tid >> 6] = d;
    __syncthreads();
    if (tid == 0) atomicAdd(num + i, __expf(sbuf[0] + sbuf[1] + sbuf[2] + sbuf[3]));
}

// ---------- final: loss = mean(log den - log num) ----------
__global__ __launch_bounds__(256) void final_kernel(
    const float* __restrict__ den, const float* __restrict__ num,
    float* __restrict__ out)
{
    const int tid = threadIdx.x;
    float v = logf(den[tid]) - logf(num[tid]);
    #pragma unroll
    for (int off = 32; off > 0; off >>= 1) v += __shfl_down(v, off);
    __shared__ float sbuf[4];
    if ((tid & 63) == 0) sbuf[tid >> 6] = v;
    __syncthreads();
    if (tid == 0) out[0] = (sbuf[0] + sbuf[1] + sbuf[2] + sbuf[3]) * (1.f / 256.f);
}

// ---------- launch ----------
extern "C" void kernel_launch(void* const* d_in, const int* in_sizes, int n_in,
                              void* d_out, int out_size, void* d_ws, size_t ws_size,
                              hipStream_t stream)
{
    (void)in_sizes; (void)n_in; (void)out_size; (void)ws_size;
    const float* a_1 = (const float*)d_in[0];
    const float* v_1 = (const float*)d_in[1];
    const float* a_2 = (const float*)d_in[2];
    const float* v_2 = (const float*)d_in[3];
    const float* W_a = (const float*)d_in[4];
    const float* W_v = (const float*)d_in[5];
    float* out = (float*)d_out;

    float* cur   = (float*)d_ws;
    float* den   = cur; cur += 256;
    float* num   = cur; cur += 256;
    float* Anorm = cur; cur += 262144;
    float* Vnorm = cur; cur += 262144;
    float* partA = cur; cur += (size_t)ZA * 262144;
    float* partV = cur; cur += (size_t)ZV * 262144;   // ~78 MB total

    zero_kernel<<<1, 512, 0, stream>>>(den);   // zeros den[256]+num[256]

    fgemm<1><<<4 * ZV, 512, 0, stream>>>(v_1, v_2, W_v, partV, 30);
    fgemm<0><<<4 * ZA, 512, 0, stream>>>(a_1, a_2, W_a, partA, 20);

    norm_kernel<<<1024, 256, 0, stream>>>(partA, partV, Anorm, Vnorm, ZV);
    sim_kernel<<<64, 256, 0, stream>>>(Anorm, Vnorm, den, num);
    dots_kernel<<<512, 256, 0, stream>>>(Anorm, Vnorm, num);
    final_kernel<<<1, 256, 0, stream>>>(den, num, out);
}